// Round 6
// baseline (181.722 us; speedup 1.0000x reference)
//
#include <hip/hip_runtime.h>
#include <hip/hip_bf16.h>

#define CC 64
#define HH 128
#define WW 128
#define HW (HH * WW)

typedef __attribute__((ext_vector_type(8)))  short short8;
typedef __attribute__((ext_vector_type(16))) float floatx16;

__device__ __forceinline__ unsigned short f2bf(float f) {
    unsigned u = __float_as_uint(f);
    u = (u + 0x7FFFu + ((u >> 16) & 1u)) >> 16;   // RTNE
    return (unsigned short)u;
}

// Prep: permute W_gen (o = c*9+t, c = cg*32+m) into Wbp[((cg*9+t)*32+m)*64+k]
// (bf16) and bias into bgp[(cg*9+t)*32+m], so main-kernel chunk (cg,t) reads
// 32 dense rows = one tap x 32 channels, and the 32x32 MFMA C-layout directly
// matches the combine/store layout (col = pixel, m-row = channel).
__global__ void ACDA_prep_kernel(const float* __restrict__ Wg,
                                 const float* __restrict__ bg,
                                 unsigned short* __restrict__ Wbp,
                                 float* __restrict__ bgp) {
    int i = blockIdx.x * 256 + threadIdx.x;
    if (i < 576 * 64) {
        int k = i & 63, row = i >> 6;
        int cg = row / 288, rem = row - cg * 288;
        int t = rem >> 5, m = rem & 31;
        int o = (cg * 32 + m) * 9 + t;
        Wbp[row * 64 + k] = f2bf(Wg[o * 64 + k]);
    }
    if (i < 576) {
        int cg = i / 288, rem = i - cg * 288;
        int t = rem >> 5, m = rem & 31;
        bgp[i] = bg[(cg * 32 + m) * 9 + t];
    }
}

// Fused filter-gen GEMM (32x32x16 bf16 MFMA, bias via C-init) + relu + 3x3
// dynamic combine, all in registers. Wave = 32 channels x 32 pixels; chunk t
// = one kk-tap for all 32 channels (permuted A). Every global access is
// >=128B-contiguous aligned segments. No LDS, no barriers, no DS ops.
__global__ __launch_bounds__(256, 4) void ACDA_main_kernel(
    const float* __restrict__ x, const unsigned short* __restrict__ Wbp,
    const float* __restrict__ bgp, float* __restrict__ out)
{
    const int tid  = threadIdx.x;
    const int wv   = tid >> 6;
    const int lane = tid & 63;
    const int lo   = lane & 31;      // pixel within 32-px group (MFMA col)
    const int hi   = lane >> 5;      // half-wave (enters MFMA m-row formula)

    const int cg = wv >> 1;          // 32-channel group (0..1)
    const int pg = wv & 1;           // 32-pixel group within 64-px segment

    const int bid = blockIdx.x;      // 2048 blocks = 8/CU
    const int b   = bid & 7;         // batch == XCD slot (L2 locality)
    const int j   = bid >> 3;
    const int seg = j & 1;
    const int h   = (j >> 1) & 127;
    const int w0  = seg * 64 + pg * 32;   // 32-px group base (0/32/64/96)

    const float* __restrict__ xb = x + (size_t)b * CC * HW;

    // ---- B fragments: X tile (64 K-channels x 32 pixels), bf16 ----
    // B[k][n]: n = lane&31 (pixel), k = (lane>>5)*8 + j (channel within slice)
    short8 bfrag[4];
#pragma unroll
    for (int s = 0; s < 4; ++s) {
        short8 v;
#pragma unroll
        for (int jj = 0; jj < 8; jj += 2) {
            const int ci = s * 16 + hi * 8 + jj;
            float f0 = xb[(ci * HH + h) * WW + w0 + lo];
            float f1 = xb[((ci + 1) * HH + h) * WW + w0 + lo];
            __hip_bfloat162 p = __float22bfloat162_rn(make_float2(f0, f1));
            unsigned u;
            __builtin_memcpy(&u, &p, 4);
            v[jj]     = (short)(u & 0xffffu);
            v[jj + 1] = (short)(u >> 16);
        }
        bfrag[s] = v;
    }

    // ---- per-lane element offsets: pofsC[r] = c(r,hi)*HW + w0 + lo ----
    // c = cg*32 + mrow, mrow = (r&3) + 8*(r>>2) + 4*hi  (MFMA C m-row)
    unsigned pofsC[16];
#pragma unroll
    for (int r = 0; r < 16; ++r) {
        const int mrow = (r & 3) + 8 * (r >> 2) + 4 * hi;
        pofsC[r] = (unsigned)((cg * 32 + mrow) * HW + w0 + lo);
    }
    const bool badL = (w0 == 0)  && (lo == 0);
    const bool badR = (w0 == 96) && (lo == 31);
    const int dneg = badL ? 0 : -1;   // clamped left-shift (masked anyway)
    const int dpos = badR ? 0 : 1;    // clamped right-shift (masked anyway)

    float oacc[16];
#pragma unroll
    for (int r = 0; r < 16; ++r) oacc[r] = 0.f;

    // ---- 9 chunks: one 3x3 tap x 32 channels each ----
#pragma unroll
    for (int t = 0; t < 9; ++t) {
        const int di  = t / 3;
        const int dj  = t - 3 * di;
        const int row = h + di - 1;
        if (row >= 0 && row < HH) {       // wave-uniform edge skip (patch==0)
            // A[m][k]: m = lo (permuted filter row), k = hi*8 + j
            const unsigned short* wbase =
                Wbp + (((cg * 9 + t) * 32 + lo) * 64 + hi * 8);
            short8 a0 = *(const short8*)(wbase);
            short8 a1 = *(const short8*)(wbase + 16);
            short8 a2 = *(const short8*)(wbase + 32);
            short8 a3 = *(const short8*)(wbase + 48);

            // bias as C-init: acc[r] = bgp[chunk*32 + mrow(r,hi)]
            const float* bb = bgp + (cg * 9 + t) * 32 + 4 * hi;
            float4 b0 = *(const float4*)(bb);
            float4 b1 = *(const float4*)(bb + 8);
            float4 b2 = *(const float4*)(bb + 16);
            float4 b3 = *(const float4*)(bb + 24);
            floatx16 acc;
            acc[0]=b0.x;  acc[1]=b0.y;  acc[2]=b0.z;  acc[3]=b0.w;
            acc[4]=b1.x;  acc[5]=b1.y;  acc[6]=b1.z;  acc[7]=b1.w;
            acc[8]=b2.x;  acc[9]=b2.y;  acc[10]=b2.z; acc[11]=b2.w;
            acc[12]=b3.x; acc[13]=b3.y; acc[14]=b3.z; acc[15]=b3.w;

            acc = __builtin_amdgcn_mfma_f32_32x32x16_bf16(a0, bfrag[0], acc, 0, 0, 0);
            acc = __builtin_amdgcn_mfma_f32_32x32x16_bf16(a1, bfrag[1], acc, 0, 0, 0);
            acc = __builtin_amdgcn_mfma_f32_32x32x16_bf16(a2, bfrag[2], acc, 0, 0, 0);
            acc = __builtin_amdgcn_mfma_f32_32x32x16_bf16(a3, bfrag[3], acc, 0, 0, 0);

            // combine: patch loads are SGPR row-base + per-lane offset (+-1)
            const float* __restrict__ rp = xb + row * WW;
            const int dd = (dj == 0) ? dneg : ((dj == 2) ? dpos : 0);
#pragma unroll
            for (int r = 0; r < 16; ++r) {
                float pv = rp[pofsC[r] + dd];
                if (dj == 0) pv = badL ? 0.f : pv;
                if (dj == 2) pv = badR ? 0.f : pv;
                float fv = fmaxf(acc[r], 0.f);
                oacc[r] = fmaf(fv, pv, oacc[r]);
            }
        }
    }

    // ---- store: per r, two 128B aligned segments (c plane, row h) ----
    float* __restrict__ ob = out + (size_t)b * CC * HW + h * WW;
#pragma unroll
    for (int r = 0; r < 16; ++r)
        ob[pofsC[r]] = oacc[r];
}

extern "C" void kernel_launch(void* const* d_in, const int* in_sizes, int n_in,
                              void* d_out, int out_size, void* d_ws, size_t ws_size,
                              hipStream_t stream) {
    const float* x  = (const float*)d_in[0];
    const float* Wg = (const float*)d_in[1];
    const float* bg = (const float*)d_in[2];
    float* out = (float*)d_out;
    unsigned short* Wbp = (unsigned short*)d_ws;            // 73728 B
    float* bgp = (float*)((char*)d_ws + 576 * 64 * 2);      // 2304 B

    ACDA_prep_kernel<<<dim3(144), dim3(256), 0, stream>>>(Wg, bg, Wbp, bgp);
    ACDA_main_kernel<<<dim3(8 * 128 * 2), dim3(256), 0, stream>>>(x, Wbp, bgp, out);
}

// Round 7
// 143.526 us; speedup vs baseline: 1.2661x; 1.2661x over previous
//
#include <hip/hip_runtime.h>
#include <hip/hip_bf16.h>

#define CC 64
#define HH 128
#define WW 128
#define HW (HH * WW)

typedef __attribute__((ext_vector_type(8)))  short short8;
typedef __attribute__((ext_vector_type(16))) float floatx16;

__device__ __forceinline__ unsigned short f2bf(float f) {
    unsigned u = __float_as_uint(f);
    u = (u + 0x7FFFu + ((u >> 16) & 1u)) >> 16;   // RTNE
    return (unsigned short)u;
}

// Prep: permute W_gen (o = c*9+t, c = cg*32+m) into Wbp[((cg*9+t)*32+m)*64+k]
// (bf16) and bias into bgp[(cg*9+t)*32+m], so main-kernel chunk (cg,t) reads
// 32 dense rows = one tap x 32 channels, and the 32x32 MFMA C-layout directly
// matches the combine/store layout (col = pixel, m-row = channel).
__global__ void ACDA_prep_kernel(const float* __restrict__ Wg,
                                 const float* __restrict__ bg,
                                 unsigned short* __restrict__ Wbp,
                                 float* __restrict__ bgp) {
    int i = blockIdx.x * 256 + threadIdx.x;
    if (i < 576 * 64) {
        int k = i & 63, row = i >> 6;
        int cg = row / 288, rem = row - cg * 288;
        int t = rem >> 5, m = rem & 31;
        int o = (cg * 32 + m) * 9 + t;
        Wbp[row * 64 + k] = f2bf(Wg[o * 64 + k]);
    }
    if (i < 576) {
        int cg = i / 288, rem = i - cg * 288;
        int t = rem >> 5, m = rem & 31;
        bgp[i] = bg[(cg * 32 + m) * 9 + t];
    }
}

// Fused filter-gen GEMM (32x32x16 bf16 MFMA, bias via C-init) + relu + 3x3
// dynamic combine, all in registers. Wave = 32 channels x 32 pixels; chunk t
// = one kk-tap for all 32 channels (permuted A). Every global access is
// >=128B-contiguous aligned segments. No LDS, no barriers, no DS ops.
// NOTE: plain __launch_bounds__(256) — the (256,4) variant capped the unified
// VGPR+AGPR budget at 128/wave and forced scratch spills (WRITE_SIZE 33->114MB).
__global__ __launch_bounds__(256) void ACDA_main_kernel(
    const float* __restrict__ x, const unsigned short* __restrict__ Wbp,
    const float* __restrict__ bgp, float* __restrict__ out)
{
    const int tid  = threadIdx.x;
    const int wv   = tid >> 6;
    const int lane = tid & 63;
    const int lo   = lane & 31;      // pixel within 32-px group (MFMA col)
    const int hi   = lane >> 5;      // half-wave (enters MFMA m-row formula)

    const int cg = wv >> 1;          // 32-channel group (0..1)
    const int pg = wv & 1;           // 32-pixel group within 64-px segment

    const int bid = blockIdx.x;      // 2048 blocks = 8/CU
    const int b   = bid & 7;         // batch == XCD slot (L2 locality)
    const int j   = bid >> 3;
    const int seg = j & 1;
    const int h   = (j >> 1) & 127;
    const int w0  = seg * 64 + pg * 32;   // 32-px group base (0/32/64/96)

    const float* __restrict__ xb = x + (size_t)b * CC * HW;

    // ---- B fragments: X tile (64 K-channels x 32 pixels), bf16 ----
    // B[k][n]: n = lane&31 (pixel), k = (lane>>5)*8 + j (channel within slice)
    short8 bfrag[4];
#pragma unroll
    for (int s = 0; s < 4; ++s) {
        short8 v;
#pragma unroll
        for (int jj = 0; jj < 8; jj += 2) {
            const int ci = s * 16 + hi * 8 + jj;
            float f0 = xb[(ci * HH + h) * WW + w0 + lo];
            float f1 = xb[((ci + 1) * HH + h) * WW + w0 + lo];
            __hip_bfloat162 p = __float22bfloat162_rn(make_float2(f0, f1));
            unsigned u;
            __builtin_memcpy(&u, &p, 4);
            v[jj]     = (short)(u & 0xffffu);
            v[jj + 1] = (short)(u >> 16);
        }
        bfrag[s] = v;
    }

    // ---- per-lane element offsets: pofsC[r] = c(r,hi)*HW + w0 + lo ----
    // c = cg*32 + mrow, mrow = (r&3) + 8*(r>>2) + 4*hi  (MFMA C m-row)
    unsigned pofsC[16];
#pragma unroll
    for (int r = 0; r < 16; ++r) {
        const int mrow = (r & 3) + 8 * (r >> 2) + 4 * hi;
        pofsC[r] = (unsigned)((cg * 32 + mrow) * HW + w0 + lo);
    }
    const bool badL = (w0 == 0)  && (lo == 0);
    const bool badR = (w0 == 96) && (lo == 31);
    const int dneg = badL ? 0 : -1;   // clamped left-shift (masked anyway)
    const int dpos = badR ? 0 : 1;    // clamped right-shift (masked anyway)

    float oacc[16];
#pragma unroll
    for (int r = 0; r < 16; ++r) oacc[r] = 0.f;

    // ---- 9 chunks: one 3x3 tap x 32 channels each ----
#pragma unroll
    for (int t = 0; t < 9; ++t) {
        const int di  = t / 3;
        const int dj  = t - 3 * di;
        const int row = h + di - 1;
        if (row >= 0 && row < HH) {       // wave-uniform edge skip (patch==0)
            // A[m][k]: m = lo (permuted filter row), k = hi*8 + j
            const unsigned short* wbase =
                Wbp + (((cg * 9 + t) * 32 + lo) * 64 + hi * 8);
            short8 a0 = *(const short8*)(wbase);
            short8 a1 = *(const short8*)(wbase + 16);
            short8 a2 = *(const short8*)(wbase + 32);
            short8 a3 = *(const short8*)(wbase + 48);

            // bias as C-init: acc[r] = bgp[chunk*32 + mrow(r,hi)]
            const float* bb = bgp + (cg * 9 + t) * 32 + 4 * hi;
            float4 b0 = *(const float4*)(bb);
            float4 b1 = *(const float4*)(bb + 8);
            float4 b2 = *(const float4*)(bb + 16);
            float4 b3 = *(const float4*)(bb + 24);
            floatx16 acc;
            acc[0]=b0.x;  acc[1]=b0.y;  acc[2]=b0.z;  acc[3]=b0.w;
            acc[4]=b1.x;  acc[5]=b1.y;  acc[6]=b1.z;  acc[7]=b1.w;
            acc[8]=b2.x;  acc[9]=b2.y;  acc[10]=b2.z; acc[11]=b2.w;
            acc[12]=b3.x; acc[13]=b3.y; acc[14]=b3.z; acc[15]=b3.w;

            acc = __builtin_amdgcn_mfma_f32_32x32x16_bf16(a0, bfrag[0], acc, 0, 0, 0);
            acc = __builtin_amdgcn_mfma_f32_32x32x16_bf16(a1, bfrag[1], acc, 0, 0, 0);
            acc = __builtin_amdgcn_mfma_f32_32x32x16_bf16(a2, bfrag[2], acc, 0, 0, 0);
            acc = __builtin_amdgcn_mfma_f32_32x32x16_bf16(a3, bfrag[3], acc, 0, 0, 0);

            // combine: patch loads are SGPR row-base + per-lane offset (+-1)
            const float* __restrict__ rp = xb + row * WW;
            const int dd = (dj == 0) ? dneg : ((dj == 2) ? dpos : 0);
#pragma unroll
            for (int r = 0; r < 16; ++r) {
                float pv = rp[pofsC[r] + dd];
                if (dj == 0) pv = badL ? 0.f : pv;
                if (dj == 2) pv = badR ? 0.f : pv;
                float fv = fmaxf(acc[r], 0.f);
                oacc[r] = fmaf(fv, pv, oacc[r]);
            }
        }
    }

    // ---- store: per r, two 128B aligned segments (c plane, row h) ----
    float* __restrict__ ob = out + (size_t)b * CC * HW + h * WW;
#pragma unroll
    for (int r = 0; r < 16; ++r)
        ob[pofsC[r]] = oacc[r];
}

extern "C" void kernel_launch(void* const* d_in, const int* in_sizes, int n_in,
                              void* d_out, int out_size, void* d_ws, size_t ws_size,
                              hipStream_t stream) {
    const float* x  = (const float*)d_in[0];
    const float* Wg = (const float*)d_in[1];
    const float* bg = (const float*)d_in[2];
    float* out = (float*)d_out;
    unsigned short* Wbp = (unsigned short*)d_ws;            // 73728 B
    float* bgp = (float*)((char*)d_ws + 576 * 64 * 2);      // 2304 B

    ACDA_prep_kernel<<<dim3(144), dim3(256), 0, stream>>>(Wg, bg, Wbp, bgp);
    ACDA_main_kernel<<<dim3(8 * 128 * 2), dim3(256), 0, stream>>>(x, Wbp, bgp, out);
}